// Round 9
// baseline (104.212 us; speedup 1.0000x reference)
//
#include <hip/hip_runtime.h>
#include <hip/hip_fp16.h>

#define CIN 64
#define COUT 32

typedef __attribute__((ext_vector_type(8))) short bf16x8;
typedef __attribute__((ext_vector_type(4))) float f32x4;

__device__ inline ushort f2bf(float x) {
    union { float f; unsigned u; } v; v.f = x;
    unsigned r = v.u + 0x7fff + ((v.u >> 16) & 1);   // RNE
    return (ushort)(r >> 16);
}

// Zero the fp16 accumulator buffer (uint4 = 8 halves per thread).
__global__ __launch_bounds__(256) void zero16_kernel(uint4* __restrict__ p, int n16)
{
    int i = blockIdx.x * blockDim.x + threadIdx.x;
    if (i < n16) p[i] = uint4{0u, 0u, 0u, 0u};
}

// Fused MFMA gather-GEMM -> packed v2f16 atomic scatter, software-pipelined:
// next tile's idx+feats loads are issued BEFORE this tile's atomics so the
// pre-MFMA vmcnt wait never drains atomic round-trips (vmcnt retires in
// order). Atomics via unsafeAtomicAdd (non-returning pk_add_f16, no memory
// clobber -> compiler may schedule loads across them).
__global__ __launch_bounds__(256) void mfma_scatter_pk_kernel(
    const float* __restrict__ feats,     // [N_IN][64] fp32
    const float* __restrict__ weight,    // [K][64][32] fp32
    const int* __restrict__ in_idx,
    const int* __restrict__ out_idx,
    ushort* __restrict__ outh,           // [n_out][32] fp16 accumulator
    int P, int ntiles, int waves_per_k)
{
    const int k    = blockIdx.y;
    const int lane = threadIdx.x & 63;
    const int wav  = blockIdx.x * (blockDim.x >> 6) + (threadIdx.x >> 6);
    const int col  = lane & 15;
    const int kch  = lane >> 4;          // 0..3

    // B fragments: bfrag[ks][h] covers k = ks*32+kch*8+e, out channel 2*col+h.
    bf16x8 bfrag[2][2];
    const float* __restrict__ Wk = weight + (long)k * CIN * COUT;
    #pragma unroll
    for (int ks = 0; ks < 2; ++ks)
        #pragma unroll
        for (int h = 0; h < 2; ++h) {
            bf16x8 t;
            #pragma unroll
            for (int e = 0; e < 8; ++e)
                t[e] = (short)f2bf(Wk[(ks * 32 + kch * 8 + e) * COUT + 2 * col + h]);
            bfrag[ks][h] = t;
        }

    const int base = k * P;

    int tile = wav;
    if (tile >= ntiles) return;

    // Prologue: loads for first tile.
    int pA  = min((tile << 4) + col, P - 1);
    int row = in_idx[base + pA];
    int oidx = out_idx[base + pA];
    const float* ar = feats + (long)row * CIN + kch * 8;
    float4 f0 = *reinterpret_cast<const float4*>(ar);
    float4 f1 = *reinterpret_cast<const float4*>(ar + 4);
    float4 f2 = *reinterpret_cast<const float4*>(ar + 32);
    float4 f3 = *reinterpret_cast<const float4*>(ar + 36);

    while (tile < ntiles) {
        const int p0    = tile << 4;
        const int my_o  = oidx;
        float4 c0 = f0, c1 = f1, c2 = f2, c3 = f3;

        // Prefetch next tile (issued before this tile's atomics).
        const int next = tile + waves_per_k;
        if (next < ntiles) {
            pA   = min((next << 4) + col, P - 1);
            row  = in_idx[base + pA];
            oidx = out_idx[base + pA];
            ar = feats + (long)row * CIN + kch * 8;
            f0 = *reinterpret_cast<const float4*>(ar);
            f1 = *reinterpret_cast<const float4*>(ar + 4);
            f2 = *reinterpret_cast<const float4*>(ar + 32);
            f3 = *reinterpret_cast<const float4*>(ar + 36);
        }

        // Convert current tile to bf16 fragments.
        bf16x8 a0, a1;
        a0[0] = (short)f2bf(c0.x); a0[1] = (short)f2bf(c0.y);
        a0[2] = (short)f2bf(c0.z); a0[3] = (short)f2bf(c0.w);
        a0[4] = (short)f2bf(c1.x); a0[5] = (short)f2bf(c1.y);
        a0[6] = (short)f2bf(c1.z); a0[7] = (short)f2bf(c1.w);
        a1[0] = (short)f2bf(c2.x); a1[1] = (short)f2bf(c2.y);
        a1[2] = (short)f2bf(c2.z); a1[3] = (short)f2bf(c2.w);
        a1[4] = (short)f2bf(c3.x); a1[5] = (short)f2bf(c3.y);
        a1[6] = (short)f2bf(c3.z); a1[7] = (short)f2bf(c3.w);

        f32x4 acc0 = {0.f, 0.f, 0.f, 0.f};
        f32x4 acc1 = {0.f, 0.f, 0.f, 0.f};
        acc0 = __builtin_amdgcn_mfma_f32_16x16x32_bf16(a0, bfrag[0][0], acc0, 0, 0, 0);
        acc0 = __builtin_amdgcn_mfma_f32_16x16x32_bf16(a1, bfrag[1][0], acc0, 0, 0, 0);
        acc1 = __builtin_amdgcn_mfma_f32_16x16x32_bf16(a0, bfrag[0][1], acc1, 0, 0, 0);
        acc1 = __builtin_amdgcn_mfma_f32_16x16x32_bf16(a1, bfrag[1][1], acc1, 0, 0, 0);

        // Scatter: acc row r = pair p0 + kch*4 + r; out row via shuffle from
        // the lane that loaded it. 16 lanes/row at contiguous 4B stride ->
        // HW merges into one 64B line-RMW per row.
        #pragma unroll
        for (int r = 0; r < 4; ++r) {
            const int prow = p0 + kch * 4 + r;
            const int orow = __shfl(my_o, kch * 4 + r, 64);
            if (prow < P) {
                __half2 v = __floats2half2_rn(acc0[r], acc1[r]);
                __half2* dst = reinterpret_cast<__half2*>(
                    outh + (long)orow * COUT + 2 * col);
                unsafeAtomicAdd(dst, v);
            }
        }
        tile = next;
    }
}

// out[i] = fp32(outh[i]) + bias[ch], 4 channels per thread.
__global__ __launch_bounds__(256) void finalize_kernel(
    const unsigned* __restrict__ outh_u, const float* __restrict__ bias,
    float* __restrict__ out, int n4)
{
    int i = blockIdx.x * blockDim.x + threadIdx.x;
    if (i < n4) {
        unsigned u0 = outh_u[2 * i], u1 = outh_u[2 * i + 1];
        int ch = (i * 4) & (COUT - 1);
        union { unsigned u; _Float16 h[2]; } a, b;
        a.u = u0; b.u = u1;
        float4 o;
        o.x = (float)a.h[0] + bias[ch + 0];
        o.y = (float)a.h[1] + bias[ch + 1];
        o.z = (float)b.h[0] + bias[ch + 2];
        o.w = (float)b.h[1] + bias[ch + 3];
        reinterpret_cast<float4*>(out)[i] = o;
    }
}

// ============ Fallback (R2 atomic path, no workspace) ============

__global__ __launch_bounds__(256) void bias_init_kernel(
    float* __restrict__ out, const float* __restrict__ bias, int total)
{
    int i = (blockIdx.x * blockDim.x + threadIdx.x) * 4;
    if (i < total) {
        int ch = i & (COUT - 1);
        float4 b;
        b.x = bias[ch + 0]; b.y = bias[ch + 1];
        b.z = bias[ch + 2]; b.w = bias[ch + 3];
        *reinterpret_cast<float4*>(out + i) = b;
    }
}

__global__ __launch_bounds__(256) void scatter_gemm_kernel(
    const float* __restrict__ feats,
    const float* __restrict__ weight,
    const int* __restrict__ in_idx,
    const int* __restrict__ out_idx,
    float* __restrict__ out,
    int P, int n_groups)
{
    const int k        = blockIdx.y;
    const int lane     = threadIdx.x & 31;
    const int group_id = blockIdx.x * (blockDim.x >> 5) + (threadIdx.x >> 5);

    float w[CIN];
    const float* __restrict__ Wk = weight + (long)k * CIN * COUT;
    #pragma unroll
    for (int c = 0; c < CIN; ++c) w[c] = Wk[c * COUT + lane];

    const int base    = k * P;
    const int nchunks = (P + 31) >> 5;
    for (int ch = group_id; ch < nchunks; ch += n_groups) {
        const int p0 = ch << 5;
        const int n  = min(32, P - p0);
        int my_in = 0, my_out = 0;
        if (lane < n) {
            my_in  = in_idx[base + p0 + lane];
            my_out = out_idx[base + p0 + lane];
        }
        #pragma unroll 4
        for (int j = 0; j < n; ++j) {
            const int in = __shfl(my_in,  j, 32);
            const int o  = __shfl(my_out, j, 32);
            const float4* __restrict__ fr =
                reinterpret_cast<const float4*>(feats + (long)in * CIN);
            float acc = 0.0f;
            #pragma unroll
            for (int c4 = 0; c4 < CIN / 4; ++c4) {
                float4 f = fr[c4];
                acc += f.x * w[4 * c4 + 0];
                acc += f.y * w[4 * c4 + 1];
                acc += f.z * w[4 * c4 + 2];
                acc += f.w * w[4 * c4 + 3];
            }
            atomicAdd(out + (long)o * COUT + lane, acc);
        }
    }
}

// ============ launch ============

extern "C" void kernel_launch(void* const* d_in, const int* in_sizes, int n_in,
                              void* d_out, int out_size, void* d_ws, size_t ws_size,
                              hipStream_t stream) {
    const float* feats   = (const float*)d_in[0];
    const float* weight  = (const float*)d_in[1];
    const float* bias    = (const float*)d_in[2];
    const int*   in_idx  = (const int*)d_in[3];
    const int*   out_idx = (const int*)d_in[4];
    float*       out     = (float*)d_out;

    const int K = in_sizes[1] / (CIN * COUT);  // 27
    const int P = in_sizes[3] / K;             // 50000

    // ws: fp16 accumulator only.
    size_t need = (size_t)out_size * 2;

    if (need > ws_size || (out_size & 7) != 0) {
        int total4 = out_size / 4;
        bias_init_kernel<<<(total4 + 255) / 256, 256, 0, stream>>>(out, bias, out_size);
        const int blocks_x = 96;
        const int n_groups = blocks_x * (256 / 32);
        dim3 grid(blocks_x, K);
        scatter_gemm_kernel<<<grid, 256, 0, stream>>>(feats, weight, in_idx, out_idx,
                                                      out, P, n_groups);
        return;
    }

    ushort* outh = (ushort*)d_ws;

    // Zero fp16 accumulator.
    {
        int n16 = (out_size * 2) / 16;
        zero16_kernel<<<(n16 + 255) / 256, 256, 0, stream>>>((uint4*)outh, n16);
    }

    // Fused gather-GEMM + pipelined pk-f16 atomic scatter.
    {
        const int ntiles      = (P + 15) / 16;
        const int blocks_x    = 196;
        const int waves_per_k = blocks_x * 4;
        dim3 grid(blocks_x, K);
        mfma_scatter_pk_kernel<<<grid, 256, 0, stream>>>(feats, weight, in_idx,
                                                         out_idx, outh, P, ntiles,
                                                         waves_per_k);
    }

    // Finalize: widen + bias.
    finalize_kernel<<<(out_size / 4 + 255) / 256, 256, 0, stream>>>(
        (const unsigned*)outh, bias, out, out_size / 4);
}

// Round 10
// 103.499 us; speedup vs baseline: 1.0069x; 1.0069x over previous
//
#include <hip/hip_runtime.h>
#include <hip/hip_fp16.h>

#define CIN 64
#define COUT 32

typedef __attribute__((ext_vector_type(8))) short bf16x8;
typedef __attribute__((ext_vector_type(4))) float f32x4;

__device__ inline ushort f2bf(float x) {
    union { float f; unsigned u; } v; v.f = x;
    unsigned r = v.u + 0x7fff + ((v.u >> 16) & 1);   // RNE
    return (ushort)(r >> 16);
}

// Init fp16 accumulator with bias (8 halves = 1 uint4 per thread).
__global__ __launch_bounds__(256) void init_bias16_kernel(
    uint4* __restrict__ p, const float* __restrict__ bias, int n16)
{
    int i = blockIdx.x * blockDim.x + threadIdx.x;
    if (i < n16) {
        int ch = (i * 8) & (COUT - 1);
        union { uint4 v; __half h[8]; } u;
        #pragma unroll
        for (int j = 0; j < 8; ++j) u.h[j] = __float2half(bias[ch + j]);
        p[i] = u.v;
    }
}

// Fused MFMA gather-GEMM -> packed v2f16 atomic scatter.
// 2 tiles (32 pairs) per wave iteration: 8 MFMAs, 8 atomic instructions in
// flight between waits. Scatter pattern: per output row, 16 lanes at
// contiguous 4B stride -> one 64B line-RMW per pair (R6/R7 established this
// is the currency).
__global__ __launch_bounds__(256) void mfma_scatter_pk_kernel(
    const float* __restrict__ feats,     // [N_IN][64] fp32
    const float* __restrict__ weight,    // [K][64][32] fp32
    const int* __restrict__ in_idx,
    const int* __restrict__ out_idx,
    ushort* __restrict__ outh,           // [n_out][32] fp16 accumulator
    int P, int npairs, int waves_per_k)
{
    const int k    = blockIdx.y;
    const int lane = threadIdx.x & 63;
    const int wav  = blockIdx.x * (blockDim.x >> 6) + (threadIdx.x >> 6);
    const int col  = lane & 15;
    const int kch  = lane >> 4;          // 0..3

    // B fragments: bfrag[ks][h] covers k = ks*32+kch*8+e, out channel 2*col+h.
    bf16x8 bfrag[2][2];
    const float* __restrict__ Wk = weight + (long)k * CIN * COUT;
    #pragma unroll
    for (int ks = 0; ks < 2; ++ks)
        #pragma unroll
        for (int h = 0; h < 2; ++h) {
            bf16x8 t;
            #pragma unroll
            for (int e = 0; e < 8; ++e)
                t[e] = (short)f2bf(Wk[(ks * 32 + kch * 8 + e) * COUT + 2 * col + h]);
            bfrag[ks][h] = t;
        }

    const int base   = k * P;
    const int ntiles = (P + 15) >> 4;

    for (int pr = wav; pr < npairs; pr += waves_per_k) {
        const int tile0 = 2 * pr;
        const int tile1 = 2 * pr + 1;
        const bool has1 = (tile1 < ntiles);

        // Coalesced idx loads for both tiles.
        const int pA0 = min((tile0 << 4) + col, P - 1);
        const int row0 = in_idx[base + pA0];
        const int o0   = out_idx[base + pA0];
        const int pA1 = has1 ? min((tile1 << 4) + col, P - 1) : pA0;
        const int row1 = has1 ? in_idx[base + pA1] : 0;
        const int o1   = has1 ? out_idx[base + pA1] : 0;

        // Gather both tiles' A rows (independent load streams).
        const float* ar0 = feats + (long)row0 * CIN + kch * 8;
        float4 x0 = *reinterpret_cast<const float4*>(ar0);
        float4 x1 = *reinterpret_cast<const float4*>(ar0 + 4);
        float4 x2 = *reinterpret_cast<const float4*>(ar0 + 32);
        float4 x3 = *reinterpret_cast<const float4*>(ar0 + 36);
        float4 y0, y1, y2, y3;
        if (has1) {
            const float* ar1 = feats + (long)row1 * CIN + kch * 8;
            y0 = *reinterpret_cast<const float4*>(ar1);
            y1 = *reinterpret_cast<const float4*>(ar1 + 4);
            y2 = *reinterpret_cast<const float4*>(ar1 + 32);
            y3 = *reinterpret_cast<const float4*>(ar1 + 36);
        }

        // Tile 0 compute.
        bf16x8 a0, a1;
        a0[0] = (short)f2bf(x0.x); a0[1] = (short)f2bf(x0.y);
        a0[2] = (short)f2bf(x0.z); a0[3] = (short)f2bf(x0.w);
        a0[4] = (short)f2bf(x1.x); a0[5] = (short)f2bf(x1.y);
        a0[6] = (short)f2bf(x1.z); a0[7] = (short)f2bf(x1.w);
        a1[0] = (short)f2bf(x2.x); a1[1] = (short)f2bf(x2.y);
        a1[2] = (short)f2bf(x2.z); a1[3] = (short)f2bf(x2.w);
        a1[4] = (short)f2bf(x3.x); a1[5] = (short)f2bf(x3.y);
        a1[6] = (short)f2bf(x3.z); a1[7] = (short)f2bf(x3.w);

        f32x4 p00 = {0.f, 0.f, 0.f, 0.f}, p01 = {0.f, 0.f, 0.f, 0.f};
        p00 = __builtin_amdgcn_mfma_f32_16x16x32_bf16(a0, bfrag[0][0], p00, 0, 0, 0);
        p00 = __builtin_amdgcn_mfma_f32_16x16x32_bf16(a1, bfrag[1][0], p00, 0, 0, 0);
        p01 = __builtin_amdgcn_mfma_f32_16x16x32_bf16(a0, bfrag[0][1], p01, 0, 0, 0);
        p01 = __builtin_amdgcn_mfma_f32_16x16x32_bf16(a1, bfrag[1][1], p01, 0, 0, 0);

        // Tile 1 compute.
        f32x4 p10 = {0.f, 0.f, 0.f, 0.f}, p11 = {0.f, 0.f, 0.f, 0.f};
        if (has1) {
            bf16x8 b0, b1;
            b0[0] = (short)f2bf(y0.x); b0[1] = (short)f2bf(y0.y);
            b0[2] = (short)f2bf(y0.z); b0[3] = (short)f2bf(y0.w);
            b0[4] = (short)f2bf(y1.x); b0[5] = (short)f2bf(y1.y);
            b0[6] = (short)f2bf(y1.z); b0[7] = (short)f2bf(y1.w);
            b1[0] = (short)f2bf(y2.x); b1[1] = (short)f2bf(y2.y);
            b1[2] = (short)f2bf(y2.z); b1[3] = (short)f2bf(y2.w);
            b1[4] = (short)f2bf(y3.x); b1[5] = (short)f2bf(y3.y);
            b1[6] = (short)f2bf(y3.z); b1[7] = (short)f2bf(y3.w);
            p10 = __builtin_amdgcn_mfma_f32_16x16x32_bf16(b0, bfrag[0][0], p10, 0, 0, 0);
            p10 = __builtin_amdgcn_mfma_f32_16x16x32_bf16(b1, bfrag[1][0], p10, 0, 0, 0);
            p11 = __builtin_amdgcn_mfma_f32_16x16x32_bf16(b0, bfrag[0][1], p11, 0, 0, 0);
            p11 = __builtin_amdgcn_mfma_f32_16x16x32_bf16(b1, bfrag[1][1], p11, 0, 0, 0);
        }

        // Scatter both tiles: 8 atomic instructions back-to-back.
        const int p0a = tile0 << 4;
        #pragma unroll
        for (int r = 0; r < 4; ++r) {
            const int prow = p0a + kch * 4 + r;
            const int orow = __shfl(o0, kch * 4 + r, 64);
            if (prow < P) {
                __half2 v = __floats2half2_rn(p00[r], p01[r]);
                unsafeAtomicAdd(reinterpret_cast<__half2*>(
                    outh + (long)orow * COUT + 2 * col), v);
            }
        }
        if (has1) {
            const int p0b = tile1 << 4;
            #pragma unroll
            for (int r = 0; r < 4; ++r) {
                const int prow = p0b + kch * 4 + r;
                const int orow = __shfl(o1, kch * 4 + r, 64);
                if (prow < P) {
                    __half2 v = __floats2half2_rn(p10[r], p11[r]);
                    unsafeAtomicAdd(reinterpret_cast<__half2*>(
                        outh + (long)orow * COUT + 2 * col), v);
                }
            }
        }
    }
}

// out[i] = fp32(outh[i]) (bias already folded into the accumulator init).
__global__ __launch_bounds__(256) void finalize_kernel(
    const unsigned* __restrict__ outh_u, float* __restrict__ out, int n4)
{
    int i = blockIdx.x * blockDim.x + threadIdx.x;
    if (i < n4) {
        unsigned u0 = outh_u[2 * i], u1 = outh_u[2 * i + 1];
        union { unsigned u; _Float16 h[2]; } a, b;
        a.u = u0; b.u = u1;
        float4 o;
        o.x = (float)a.h[0];
        o.y = (float)a.h[1];
        o.z = (float)b.h[0];
        o.w = (float)b.h[1];
        reinterpret_cast<float4*>(out)[i] = o;
    }
}

// ============ Fallback (R2 atomic path, no workspace) ============

__global__ __launch_bounds__(256) void bias_init_kernel(
    float* __restrict__ out, const float* __restrict__ bias, int total)
{
    int i = (blockIdx.x * blockDim.x + threadIdx.x) * 4;
    if (i < total) {
        int ch = i & (COUT - 1);
        float4 b;
        b.x = bias[ch + 0]; b.y = bias[ch + 1];
        b.z = bias[ch + 2]; b.w = bias[ch + 3];
        *reinterpret_cast<float4*>(out + i) = b;
    }
}

__global__ __launch_bounds__(256) void scatter_gemm_kernel(
    const float* __restrict__ feats,
    const float* __restrict__ weight,
    const int* __restrict__ in_idx,
    const int* __restrict__ out_idx,
    float* __restrict__ out,
    int P, int n_groups)
{
    const int k        = blockIdx.y;
    const int lane     = threadIdx.x & 31;
    const int group_id = blockIdx.x * (blockDim.x >> 5) + (threadIdx.x >> 5);

    float w[CIN];
    const float* __restrict__ Wk = weight + (long)k * CIN * COUT;
    #pragma unroll
    for (int c = 0; c < CIN; ++c) w[c] = Wk[c * COUT + lane];

    const int base    = k * P;
    const int nchunks = (P + 31) >> 5;
    for (int ch = group_id; ch < nchunks; ch += n_groups) {
        const int p0 = ch << 5;
        const int n  = min(32, P - p0);
        int my_in = 0, my_out = 0;
        if (lane < n) {
            my_in  = in_idx[base + p0 + lane];
            my_out = out_idx[base + p0 + lane];
        }
        #pragma unroll 4
        for (int j = 0; j < n; ++j) {
            const int in = __shfl(my_in,  j, 32);
            const int o  = __shfl(my_out, j, 32);
            const float4* __restrict__ fr =
                reinterpret_cast<const float4*>(feats + (long)in * CIN);
            float acc = 0.0f;
            #pragma unroll
            for (int c4 = 0; c4 < CIN / 4; ++c4) {
                float4 f = fr[c4];
                acc += f.x * w[4 * c4 + 0];
                acc += f.y * w[4 * c4 + 1];
                acc += f.z * w[4 * c4 + 2];
                acc += f.w * w[4 * c4 + 3];
            }
            atomicAdd(out + (long)o * COUT + lane, acc);
        }
    }
}

// ============ launch ============

extern "C" void kernel_launch(void* const* d_in, const int* in_sizes, int n_in,
                              void* d_out, int out_size, void* d_ws, size_t ws_size,
                              hipStream_t stream) {
    const float* feats   = (const float*)d_in[0];
    const float* weight  = (const float*)d_in[1];
    const float* bias    = (const float*)d_in[2];
    const int*   in_idx  = (const int*)d_in[3];
    const int*   out_idx = (const int*)d_in[4];
    float*       out     = (float*)d_out;

    const int K = in_sizes[1] / (CIN * COUT);  // 27
    const int P = in_sizes[3] / K;             // 50000

    // ws: fp16 accumulator only.
    size_t need = (size_t)out_size * 2;

    if (need > ws_size || (out_size & 7) != 0) {
        int total4 = out_size / 4;
        bias_init_kernel<<<(total4 + 255) / 256, 256, 0, stream>>>(out, bias, out_size);
        const int blocks_x = 96;
        const int n_groups = blocks_x * (256 / 32);
        dim3 grid(blocks_x, K);
        scatter_gemm_kernel<<<grid, 256, 0, stream>>>(feats, weight, in_idx, out_idx,
                                                      out, P, n_groups);
        return;
    }

    ushort* outh = (ushort*)d_ws;

    // Init accumulator with bias (fp16).
    {
        int n16 = (out_size * 2) / 16;
        init_bias16_kernel<<<(n16 + 255) / 256, 256, 0, stream>>>(
            (uint4*)outh, bias, n16);
    }

    // Fused gather-GEMM + pk-f16 atomic scatter, 2 tiles per wave iteration.
    {
        const int ntiles      = (P + 15) / 16;
        const int npairs      = (ntiles + 1) / 2;
        const int blocks_x    = 196;               // 784 waves/k, ~2 pairs each
        const int waves_per_k = blocks_x * 4;
        dim3 grid(blocks_x, K);
        mfma_scatter_pk_kernel<<<grid, 256, 0, stream>>>(feats, weight, in_idx,
                                                         out_idx, outh, P, npairs,
                                                         waves_per_k);
    }

    // Finalize: widen to fp32.
    finalize_kernel<<<(out_size / 4 + 255) / 256, 256, 0, stream>>>(
        (const unsigned*)outh, out, out_size / 4);
}